// Round 12
// baseline (179.803 us; speedup 1.0000x reference)
//
#include <hip/hip_runtime.h>

typedef unsigned short u16;
typedef unsigned int u32;
typedef float f32x4 __attribute__((ext_vector_type(4)));
typedef float f32x16 __attribute__((ext_vector_type(16)));
typedef __bf16 bf16x8 __attribute__((ext_vector_type(8)));
typedef int i32x4 __attribute__((ext_vector_type(4)));

#define DEV static __device__ __forceinline__

DEV u16 f2bf(float f){
  u32 u = __builtin_bit_cast(u32, f);
  u = (u + 0x7fffu + ((u >> 16) & 1u)) >> 16;
  return (u16)u;
}

DEV float fexp2(float x){
#if __has_builtin(__builtin_amdgcn_exp2f)
  return __builtin_amdgcn_exp2f(x);
#else
  return __builtin_exp2f(x);
#endif
}

DEV void async16(const void* g, void* l){
  __builtin_amdgcn_global_load_lds((const __attribute__((address_space(1))) void*)g,
                                   (__attribute__((address_space(3))) void*)l, 16, 0, 0);
}

static constexpr int NB = 2, DM = 256, NS = 4096, NH = 8, HD = 32;
// hd^-0.5 * log2(e): folded into Q so softmax uses exp2
static constexpr float QSCALE = 0.17677669529663687f * 1.4426950408889634f;
static constexpr float CAP = 24.0f;   // fixed softmax cap (exp2 units)

// ---------- fused prep: x transpose->bf16 (512 blocks) + wqkv convert (192) + wproj convert (64)
__global__ __launch_bounds__(256) void k_prep(const float* __restrict__ x, u16* __restrict__ xT,
                      const float* __restrict__ wqkv, u16* __restrict__ wqb,
                      const float* __restrict__ wproj, u16* __restrict__ wpb){
  __shared__ float tile[64][65];
  int bid = blockIdx.x, t = threadIdx.x;
  if(bid < 512){
    int b = bid >> 8, dt = (bid >> 6) & 3, nt = bid & 63;
    int tr = t >> 4, tc = t & 15;
    const float* src = x + ((size_t)b*DM + dt*64)*NS + nt*64;
#pragma unroll
    for(int rr=0; rr<4; ++rr){
      int row = rr*16 + tr;
      float4 v = *(const float4*)(src + (size_t)row*NS + tc*4);
      tile[row][tc*4+0]=v.x; tile[row][tc*4+1]=v.y; tile[row][tc*4+2]=v.z; tile[row][tc*4+3]=v.w;
    }
    __syncthreads();
#pragma unroll
    for(int rr=0; rr<4; ++rr){
      int nl = rr*16 + tr, dl = tc*4;
      ushort4 o;
      o.x = f2bf(tile[dl+0][nl]); o.y = f2bf(tile[dl+1][nl]);
      o.z = f2bf(tile[dl+2][nl]); o.w = f2bf(tile[dl+3][nl]);
      *(ushort4*)(xT + ((size_t)b*NS + nt*64 + nl)*DM + dt*64 + dl) = o;
    }
  } else {
    int cid = bid - 512;
    const float* s; u16* d; int i;
    if(cid < 192){ s = wqkv; d = wqb; i = cid*256 + t; }
    else         { s = wproj; d = wpb; i = (cid-192)*256 + t; }
    float4 v = ((const float4*)s)[i];
    ushort4 o; o.x=f2bf(v.x); o.y=f2bf(v.y); o.z=f2bf(v.z); o.w=f2bf(v.w);
    ((ushort4*)d)[i] = o;
  }
}

// ---------- GEMM: D[n][o] = A[n][:256] . W[o][:256]  (row-major bf16, K=256 LDS-resident)
// MODE 0: A=xT, W=w_qkv(768x256) -> Q(scaled)/K via LDS-transpose epilogue, Vt direct
// MODE 1: A=aout, W=w_proj(256x256) -> d_out f32 via LDS-transpose epilogue
template<int MODE>
__global__ __launch_bounds__(256) void k_gemm(const u16* __restrict__ A, const u16* __restrict__ W,
                       const float* __restrict__ bias,
                       u16* __restrict__ q, u16* __restrict__ kbuf, u16* __restrict__ vt,
                       float* __restrict__ outp){
  __shared__ __align__(16) u16 ldsA[32768];   // 128 x 256 bf16, XOR-swizzled
  __shared__ __align__(16) u16 ldsW[32768];
  int b = blockIdx.z, nt = blockIdx.x, ot = blockIdx.y;
  int tid = threadIdx.x;
  const char* Ab = (const char*)(A + ((size_t)b*NS + nt*128)*DM);
  const char* Wb = (const char*)(W + (size_t)ot*128*DM);
#pragma unroll
  for(int it=0; it<16; ++it){
    int dst = it*4096 + tid*16;
    int srcb = dst ^ (((dst >> 9) & 15) << 4);
    async16(Ab + srcb, (char*)ldsA + dst);
    async16(Wb + srcb, (char*)ldsW + dst);
  }
  __syncthreads();
  int w = tid >> 6, l = tid & 63, l15 = l & 15, g = l >> 4;
  f32x4 acc[2][8];
#pragma unroll
  for(int m=0;m<2;++m)
#pragma unroll
    for(int j=0;j<8;++j) acc[m][j] = f32x4{0.f,0.f,0.f,0.f};
#pragma unroll
  for(int kk=0; kk<8; ++kk){
    int cb = kk*64 + g*16;
    bf16x8 a[2], bb[8];
#pragma unroll
    for(int m=0;m<2;++m){
      int row = w*32 + m*16 + l15;
      a[m] = *(const bf16x8*)((const char*)ldsA + row*512 + (cb ^ ((row & 15) << 4)));
    }
#pragma unroll
    for(int j=0;j<8;++j){
      int row = j*16 + l15;
      bb[j] = *(const bf16x8*)((const char*)ldsW + row*512 + (cb ^ ((row & 15) << 4)));
    }
#pragma unroll
    for(int m=0;m<2;++m)
#pragma unroll
      for(int j=0;j<8;++j)
        acc[m][j] = __builtin_amdgcn_mfma_f32_16x16x32_bf16(a[m], bb[j], acc[m][j], 0, 0, 0);
  }

  if constexpr (MODE == 0){
    if(ot < 4){
      // Q or K: LDS [128 n][128 o] u16 transpose -> coalesced [b][h][n][d] 64B runs
      float sc = (ot < 2) ? QSCALE : 1.f;
      u16* dst = (ot < 2) ? q : kbuf;
      int hbase = (ot & 1) * 4;
      __syncthreads();            // all waves done reading ldsA
      char* tile = (char*)ldsA;   // 32KB used
#pragma unroll
      for(int m=0;m<2;++m){
#pragma unroll
        for(int j=0;j<8;++j){
          int o = j*16 + l15;
          float bs = bias[ot*128 + o];
          float v0 = (acc[m][j][0]+bs)*sc, v1 = (acc[m][j][1]+bs)*sc;
          float v2 = (acc[m][j][2]+bs)*sc, v3 = (acc[m][j][3]+bs)*sc;
          u32 pA, pB;
          asm("v_cvt_pk_bf16_f32 %0, %1, %2" : "=v"(pA) : "v"(v0), "v"(v1));
          asm("v_cvt_pk_bf16_f32 %0, %1, %2" : "=v"(pB) : "v"(v2), "v"(v3));
          int n0 = w*32 + m*16 + g*4;
          *(u16*)(tile + (n0+0)*256 + ((o*2) ^ (((n0+0)&7)<<4))) = (u16)pA;
          *(u16*)(tile + (n0+1)*256 + ((o*2) ^ (((n0+1)&7)<<4))) = (u16)(pA>>16);
          *(u16*)(tile + (n0+2)*256 + ((o*2) ^ (((n0+2)&7)<<4))) = (u16)pB;
          *(u16*)(tile + (n0+3)*256 + ((o*2) ^ (((n0+3)&7)<<4))) = (u16)(pB>>16);
        }
      }
      __syncthreads();
#pragma unroll
      for(int p=0;p<2;++p){
        int seg = p*256 + tid;          // 512 segs = 128 n x 4 heads
        int hsub = seg >> 7, n_l = seg & 127;
        u16* gdst = dst + (((size_t)b*NH + hbase + hsub)*NS + nt*128 + n_l)*HD;
#pragma unroll
        for(int c=0;c<4;++c)
          *(uint4*)((char*)gdst + c*16) =
            *(const uint4*)(tile + n_l*256 + ((hsub*64 + c*16) ^ ((n_l&7)<<4)));
      }
    } else {
      // V: direct Vt[b][h][d][n] stores, 16B per lane
#pragma unroll
      for(int m=0;m<2;++m){
        int n0 = nt*128 + w*32 + m*16 + g*4;
#pragma unroll
        for(int j=0;j<8;++j){
          int o = ot*128 + j*16 + l15;
          float bs = bias[o];
          int hh = (o >> 5) & 7, dh = o & 31;
          float v0=acc[m][j][0]+bs, v1=acc[m][j][1]+bs, v2=acc[m][j][2]+bs, v3=acc[m][j][3]+bs;
          u32 pA, pB;
          asm("v_cvt_pk_bf16_f32 %0, %1, %2" : "=v"(pA) : "v"(v0), "v"(v1));
          asm("v_cvt_pk_bf16_f32 %0, %1, %2" : "=v"(pB) : "v"(v2), "v"(v3));
          uint2 pk; pk.x = pA; pk.y = pB;
          *(uint2*)(vt + (((size_t)b*NH + hh)*HD + dh)*NS + n0) = pk;
        }
      }
    }
  } else {
    // MODE 1: LDS [128 o][128 n] f32 (64KB) -> coalesced [b][o][n] stores
    __syncthreads();
    char* tileF = (char*)ldsA;
#pragma unroll
    for(int m=0;m<2;++m){
#pragma unroll
      for(int j=0;j<8;++j){
        int o = j*16 + l15;
        float bs = bias[ot*128 + o];
        f32x4 v4;
        v4[0]=acc[m][j][0]+bs; v4[1]=acc[m][j][1]+bs;
        v4[2]=acc[m][j][2]+bs; v4[3]=acc[m][j][3]+bs;
        int n0 = w*32 + m*16 + g*4;
        *(f32x4*)(tileF + o*512 + ((n0*4) ^ ((o&7)<<4))) = v4;
      }
    }
    __syncthreads();
#pragma unroll
    for(int p=0;p<4;++p){
      int idx = p*256 + tid;            // 1024 = 128 o x 8 chunks of 64B
      int o = idx >> 3, c = idx & 7;
      float* gdst = outp + ((size_t)b*DM + ot*128 + o)*NS + nt*128 + c*16;
#pragma unroll
      for(int u=0;u<4;++u)
        *(uint4*)((char*)gdst + u*16) =
          *(const uint4*)(tileF + o*512 + ((c*64 + u*16) ^ ((o&7)<<4)));
    }
  }
}

// ---------- attention v2: barrier-free main loop, direct-global K/V, 8 waves/block ----------
// Block = 512 thr = 8 waves = 2 q-subtiles (32 rows) x 4 k-streams (1024 k each, 16 rounds).
// Q/K/V are L2/L3-resident (12 MB total): no LDS staging. Single combine at the end.
__global__ __launch_bounds__(512, 6) void k_attn(const u16* __restrict__ Q, const u16* __restrict__ K,
                       const u16* __restrict__ V, u16* __restrict__ aout){
  __shared__ float scrO[2][4][32][32];   // [qsub][kq][d][q] partial O^T, 32 KB
  __shared__ float scrS[2][4][32];       // [qsub][kq][q] partial softmax sums
  __shared__ __align__(8) u16 obuf[64][36];  // padded: +8B/row kills 64B-stride conflicts
  int qt = blockIdx.x, bh = blockIdx.y;
  int tid = threadIdx.x, wid = tid >> 6, l = tid & 63, l31 = l & 31, hi = l >> 5;
  int qsub = wid & 1, kq = wid >> 1;
  const u16* Qb = Q + (size_t)bh*NS*HD;
  const u16* Kb = K + (size_t)bh*NS*HD;
  const u16* Vb = V + (size_t)bh*HD*NS;
  int q0 = qt*64 + qsub*32;

  // Q fragments (B operand): lane holds Q[q0+l31][c*16 + hi*8 + j]
  bf16x8 qf[2];
  qf[0] = *(const bf16x8*)(Qb + (size_t)(q0 + l31)*HD + hi*8);
  qf[1] = *(const bf16x8*)(Qb + (size_t)(q0 + l31)*HD + 16 + hi*8);

  // direct-global fragment base pointers for this wave's k-stream
  const u16* kp = Kb + (size_t)(kq*1024 + l31)*HD + hi*8;   // K[k][d] rows
  const u16* vp = Vb + (size_t)l31*NS + kq*1024 + hi*8;     // Vt[d][n] rows

  f32x16 OT;
#pragma unroll
  for(int r=0;r<16;++r) OT[r] = 0.f;
  f32x16 capv;
#pragma unroll
  for(int r=0;r<16;++r) capv[r] = -CAP;
  float psum = 0.f;

  for(int t=0; t<16; ++t){
#pragma unroll
    for(int s=0; s<2; ++s){
      int ks = t*64 + s*32;
      bf16x8 ka0 = *(const bf16x8*)(kp + (size_t)ks*HD);
      bf16x8 ka1 = *(const bf16x8*)(kp + (size_t)ks*HD + 16);
      f32x16 st = __builtin_amdgcn_mfma_f32_32x32x16_bf16(ka0, qf[0], capv, 0, 0, 0);
      st = __builtin_amdgcn_mfma_f32_32x32x16_bf16(ka1, qf[1], st, 0, 0, 0);
#pragma unroll
      for(int r=0;r<16;++r) st[r] = fexp2(st[r]);
      {
        float a0 = (st[0]+st[1]) + (st[2]+st[3]);
        float a1 = (st[4]+st[5]) + (st[6]+st[7]);
        float a2 = (st[8]+st[9]) + (st[10]+st[11]);
        float a3 = (st[12]+st[13]) + (st[14]+st[15]);
        psum += (a0+a1) + (a2+a3);
      }
#pragma unroll
      for(int kk=0; kk<2; ++kk){
        int rb = kk*8;
        u32 XA, XB, YA, YB;
        asm("v_cvt_pk_bf16_f32 %0, %1, %2" : "=v"(XA) : "v"(st[rb+0]), "v"(st[rb+1]));
        asm("v_cvt_pk_bf16_f32 %0, %1, %2" : "=v"(XB) : "v"(st[rb+2]), "v"(st[rb+3]));
        asm("v_cvt_pk_bf16_f32 %0, %1, %2" : "=v"(YA) : "v"(st[rb+4]), "v"(st[rb+5]));
        asm("v_cvt_pk_bf16_f32 %0, %1, %2" : "=v"(YB) : "v"(st[rb+6]), "v"(st[rb+7]));
        asm("v_permlane32_swap_b32 %0, %1" : "+v"(XA), "+v"(YA));
        asm("v_permlane32_swap_b32 %0, %1" : "+v"(XB), "+v"(YB));
        i32x4 pw; pw[0] = (int)XA; pw[1] = (int)XB; pw[2] = (int)YA; pw[3] = (int)YB;
        bf16x8 pfrag = __builtin_bit_cast(bf16x8, pw);
        bf16x8 va = *(const bf16x8*)(vp + ks + kk*16);
        OT = __builtin_amdgcn_mfma_f32_32x32x16_bf16(va, pfrag, OT, 0, 0, 0);
      }
    }
  }

  // write partials (no in-loop barriers were needed; one combine below)
  float psum2 = psum + __shfl_xor(psum, 32, 64);
#pragma unroll
  for(int r=0;r<16;++r){
    int dd = (r & 3) + 8*(r >> 2) + 4*hi;
    scrO[qsub][kq][dd][l31] = OT[r];
  }
  if(hi == 0) scrS[qsub][kq][l31] = psum2;
  __syncthreads();

  // reduce 4 k-streams -> normalized bf16, 4 outputs/thread
  {
    int qs = tid >> 8, rem = tid & 255;
    int qq = rem & 31, d0 = (rem >> 5) * 4;
    float tot = scrS[qs][0][qq] + scrS[qs][1][qq] + scrS[qs][2][qq] + scrS[qs][3][qq];
    float inv = 1.0f / tot;
    float o[4];
#pragma unroll
    for(int i=0;i<4;++i){
      int d = d0 + i;
      o[i] = (scrO[qs][0][d][qq] + scrO[qs][1][d][qq] + scrO[qs][2][d][qq] + scrO[qs][3][d][qq]) * inv;
    }
    u32 pA, pB;
    asm("v_cvt_pk_bf16_f32 %0, %1, %2" : "=v"(pA) : "v"(o[0]), "v"(o[1]));
    asm("v_cvt_pk_bf16_f32 %0, %1, %2" : "=v"(pB) : "v"(o[2]), "v"(o[3]));
    *(u32*)&obuf[qs*32 + qq][d0]     = pA;
    *(u32*)&obuf[qs*32 + qq][d0 + 2] = pB;
  }
  __syncthreads();

  // coalesced store: 64 q rows x 64B
  {
    int b = bh >> 3, h = bh & 7;
    int qq = tid >> 3, ch = tid & 7;
    uint2 vv = *(const uint2*)((const char*)&obuf[qq][0] + ch*8);
    *(uint2*)((char*)aout + (((size_t)b*NS + qt*64 + qq)*DM + h*HD)*2 + ch*8) = vv;
  }
}

extern "C" void kernel_launch(void* const* d_in, const int* in_sizes, int n_in,
                              void* d_out, int out_size, void* d_ws, size_t ws_size,
                              hipStream_t stream) {
  (void)in_sizes; (void)n_in; (void)out_size; (void)ws_size;
  const float* x     = (const float*)d_in[0];
  const float* wqkv  = (const float*)d_in[1];
  const float* bqkv  = (const float*)d_in[2];
  const float* wproj = (const float*)d_in[3];
  const float* bproj = (const float*)d_in[4];
  float* out = (float*)d_out;
  char* ws = (char*)d_ws;
  u16* xT  = (u16*)(ws);                 // 4,194,304 B
  u16* wqb = (u16*)(ws + 4194304);       //   393,216 B
  u16* wpb = (u16*)(ws + 4587520);       //   131,072 B
  u16* Q   = (u16*)(ws + 4718592);       // 4,194,304 B
  u16* K   = (u16*)(ws + 8912896);       // 4,194,304 B
  u16* Vt  = (u16*)(ws + 13107200);      // 4,194,304 B
  u16* aout = xT;                        // xT dead after QKV GEMM

  k_prep<<<768, 256, 0, stream>>>(x, xT, wqkv, wqb, wproj, wpb);
  k_gemm<0><<<dim3(32,6,2), 256, 0, stream>>>(xT, wqb, bqkv, Q, K, Vt, nullptr);
  k_attn<<<dim3(64,16), 512, 0, stream>>>(Q, K, Vt, aout);
  k_gemm<1><<<dim3(32,2,2), 256, 0, stream>>>(aout, wpb, bproj, nullptr, nullptr, nullptr, out);
}